// Round 7
// baseline (1569.795 us; speedup 1.0000x reference)
//
#include <hip/hip_runtime.h>

// out[r*64+ch] = b[ch] + sum_{edges (r,c)} W[ch][c],  r normalized by row.min().
// N = 100000, C = 64, E = 3.2M.
//
// R7: CSR eliminated. Pipeline: detect(dtype) -> transpose(W->bf16 Wt) ->
//     partition(edges -> 256-row buckets, 4B records, LDS-staged coalesced
//     flushes, folds rmin reduction) -> accum(per-bucket 64KB LDS out-tile,
//     lane=channel, 8-deep MLP Wtb gather, ds_add_f32, one coalesced store).
// ws: flags | Wtb[N*64 bf16] | gtail[nbkt*16] | ovf | recs[nbkt*segcap]

#define OVF_MAX (1 << 19)
#define NBKT_MAX 400
#define SLOTS 36
#define FLUSH_T 24
#define GT_STRIDE 16  // gtail padded to 64B/counter: same-line atomic serialization fix (R5 lesson)

__device__ __forceinline__ float bf16u_to_f(unsigned short u) {
    union { unsigned int i; float f; } x; x.i = ((unsigned int)u) << 16; return x.f;
}

// 1 block: dtype probe (head+tail odd words) + flags/gtail init.
__global__ __launch_bounds__(1024) void LINK_detect_kernel(
    const unsigned int* __restrict__ words, int E, int* __restrict__ flags,
    int* __restrict__ gtail, int nbkt, int segcap) {
    long long twoE = 2LL * E;
    int tid = threadIdx.x;
    unsigned int oddOr = 0u;
    int nscan = (int)(twoE < 8192 ? twoE : 8192);
    for (int i = tid; i < nscan; i += blockDim.x) {
        if (i & 1) oddOr |= words[i];
        long long j = twoE - 1 - i;
        if (j >= nscan && (j & 1)) oddOr |= words[j];
    }
    __shared__ unsigned int sred[16];
    for (int off = 32; off > 0; off >>= 1)
        oddOr |= (unsigned int)__shfl_down((int)oddOr, off, 64);
    int wid = tid >> 6;
    if ((tid & 63) == 0) sred[wid] = oddOr;
    __syncthreads();
    if (tid == 0) {
        unsigned int o = 0;
        for (int i = 0; i < (int)(blockDim.x >> 6); ++i) o |= sred[i];
        flags[0] = o ? 1 : 0;   // 1 = int32 layout
        flags[1] = 0x7fffffff;  // rmin (partition fills via atomicMin)
        flags[8] = 0;           // ovf count
    }
    for (int k = tid; k < nbkt; k += blockDim.x) gtail[k * GT_STRIDE] = k * segcap;
}

// W [64][N] f32 -> Wtb [N][64] bf16 (RNE) via padded LDS tile.
__global__ void LINK_transpose_kernel(const float* __restrict__ W,
                                      unsigned short* __restrict__ Wtb, int N) {
    __shared__ float tile[64][65];
    int n0 = blockIdx.x * 64;
    int lx = threadIdx.x & 63;
    int ly = threadIdx.x >> 6;
#pragma unroll
    for (int it = 0; it < 16; ++it) {
        int ch = ly + 4 * it;
        float v = 0.0f;
        if (n0 + lx < N) v = W[(size_t)ch * N + (n0 + lx)];
        tile[lx][ch] = v;
    }
    __syncthreads();
#pragma unroll
    for (int it = 0; it < 16; ++it) {
        int nn = ly + 4 * it;
        if (n0 + nn < N) {
            union { float f; unsigned int i; } x; x.f = tile[nn][lx];
            unsigned int u = x.i;
            unsigned int r = (u + 0x7fffu + ((u >> 16) & 1u)) >> 16;  // RNE
            Wtb[((size_t)(n0 + nn) << 6) + lx] = (unsigned short)r;
        }
    }
}

// Edges -> 256-row buckets. Records 4B: (r&255)<<17 | c. LDS-staged, wave-wide
// coalesced flushes. Also block-reduces rmin -> atomicMin(flags[1]).
__global__ __launch_bounds__(1024) void LINK_part_kernel(
    const unsigned int* __restrict__ words, int E, int N, int nbkt, int segcap,
    int* __restrict__ gtail, unsigned int* __restrict__ recs,
    int* __restrict__ ovf, int* __restrict__ flags) {
    __shared__ unsigned int lstage[NBKT_MAX * SLOTS];  // 57.6 KB
    __shared__ int lcnt[NBKT_MAX];
    __shared__ int sred[16];
    int tid = threadIdx.x;
    for (int k = tid; k < nbkt; k += blockDim.x) lcnt[k] = 0;
    __syncthreads();
    int isInt32 = flags[0];
    int mnr = 0x7fffffff;
    int nblk = gridDim.x;
    long long per_round = (long long)nblk * blockDim.x;
    long long nround = ((long long)E + per_round - 1) / per_round;
    int lane = tid & 63, wid = tid >> 6, nw = blockDim.x >> 6;
    for (long long rd = 0; rd < nround; ++rd) {
        long long e = (rd * nblk + blockIdx.x) * blockDim.x + tid;
        if (e < E) {
            int r, c;
            if (isInt32) { r = (int)words[e]; c = (int)words[E + e]; }
            else { r = (int)words[2 * e]; c = (int)words[2LL * E + 2 * e]; }
            mnr = min(mnr, r);
            if ((unsigned)r < (unsigned)N && (unsigned)c < (unsigned)N) {
                int k = r >> 8;
                unsigned int rec = ((unsigned int)(r & 255) << 17) | (unsigned int)c;
                int pos = atomicAdd(&lcnt[k], 1);
                if (pos < SLOTS) {
                    lstage[k * SLOTS + pos] = rec;
                } else {  // rare mid-round spill: direct global append
                    int g = atomicAdd(&gtail[k * GT_STRIDE], 1);
                    if (g < (k + 1) * segcap) recs[g] = rec;
                    else {
                        int oi = atomicAdd(&flags[8], 1);
                        if (oi < OVF_MAX) { ovf[2 * oi] = r; ovf[2 * oi + 1] = c; }
                    }
                }
            }
        }
        __syncthreads();
        bool last = (rd == nround - 1);
        for (int k = wid; k < nbkt; k += nw) {
            int cnt = lcnt[k]; if (cnt > SLOTS) cnt = SLOTS;
            if (cnt >= FLUSH_T || (last && cnt > 0)) {
                int g = 0;
                if (lane == 0) g = atomicAdd(&gtail[k * GT_STRIDE], cnt);
                g = __shfl(g, 0);
                if (lane < cnt) {
                    int gg = g + lane;
                    unsigned int rec = lstage[k * SLOTS + lane];
                    if (gg < (k + 1) * segcap) recs[gg] = rec;
                    else {
                        int oi = atomicAdd(&flags[8], 1);
                        if (oi < OVF_MAX) {
                            ovf[2 * oi] = (k << 8) | (int)(rec >> 17);
                            ovf[2 * oi + 1] = (int)(rec & 0x1FFFF);
                        }
                    }
                }
                if (lane == 0) lcnt[k] = 0;
            }
        }
        __syncthreads();
    }
    for (int off = 32; off > 0; off >>= 1) mnr = min(mnr, __shfl_down(mnr, off, 64));
    if (lane == 0) sred[wid] = mnr;
    __syncthreads();
    if (tid == 0) {
        int m = 0x7fffffff;
        for (int i = 0; i < 16; ++i) m = min(m, sred[i]);
        atomicMin(&flags[1], m);
    }
}

// One block per bucket: 256x64 fp32 LDS tile; lane=channel; 8-deep independent
// Wtb loads; ds_add_f32 (2-way bank aliasing = free); coalesced float4 store.
__global__ __launch_bounds__(1024) void LINK_accum_kernel(
    const int* __restrict__ gtail, const unsigned int* __restrict__ recs, int segcap,
    const unsigned short* __restrict__ Wtb, const float* __restrict__ bias,
    float* __restrict__ out, const int* __restrict__ flags, int N) {
    __shared__ float tile[256 * 64];  // 64 KB
    int b = blockIdx.x, tid = threadIdx.x;
    for (int i = tid; i < 16384; i += 1024) tile[i] = 0.0f;
    __syncthreads();
    int len = gtail[b * GT_STRIDE] - b * segcap;
    if (len > segcap) len = segcap;
    if (len < 0) len = 0;
    const unsigned int* rp = recs + (size_t)b * segcap;
    int lane = tid & 63, wid = tid >> 6;
    for (int base = wid * 64; base < len; base += 16 * 64) {
        int cnt = len - base; if (cnt > 64) cnt = 64;
        int rec = 0;
        if (lane < cnt) rec = (int)rp[base + lane];
        int j = 0;
        for (; j + 8 <= cnt; j += 8) {
            unsigned int r0 = (unsigned int)__shfl(rec, j + 0);
            unsigned int r1 = (unsigned int)__shfl(rec, j + 1);
            unsigned int r2 = (unsigned int)__shfl(rec, j + 2);
            unsigned int r3 = (unsigned int)__shfl(rec, j + 3);
            unsigned int r4 = (unsigned int)__shfl(rec, j + 4);
            unsigned int r5 = (unsigned int)__shfl(rec, j + 5);
            unsigned int r6 = (unsigned int)__shfl(rec, j + 6);
            unsigned int r7 = (unsigned int)__shfl(rec, j + 7);
            unsigned short u0 = Wtb[((size_t)(r0 & 0x1FFFF) << 6) + lane];
            unsigned short u1 = Wtb[((size_t)(r1 & 0x1FFFF) << 6) + lane];
            unsigned short u2 = Wtb[((size_t)(r2 & 0x1FFFF) << 6) + lane];
            unsigned short u3 = Wtb[((size_t)(r3 & 0x1FFFF) << 6) + lane];
            unsigned short u4 = Wtb[((size_t)(r4 & 0x1FFFF) << 6) + lane];
            unsigned short u5 = Wtb[((size_t)(r5 & 0x1FFFF) << 6) + lane];
            unsigned short u6 = Wtb[((size_t)(r6 & 0x1FFFF) << 6) + lane];
            unsigned short u7 = Wtb[((size_t)(r7 & 0x1FFFF) << 6) + lane];
            atomicAdd(&tile[((r0 >> 17) << 6) + lane], bf16u_to_f(u0));
            atomicAdd(&tile[((r1 >> 17) << 6) + lane], bf16u_to_f(u1));
            atomicAdd(&tile[((r2 >> 17) << 6) + lane], bf16u_to_f(u2));
            atomicAdd(&tile[((r3 >> 17) << 6) + lane], bf16u_to_f(u3));
            atomicAdd(&tile[((r4 >> 17) << 6) + lane], bf16u_to_f(u4));
            atomicAdd(&tile[((r5 >> 17) << 6) + lane], bf16u_to_f(u5));
            atomicAdd(&tile[((r6 >> 17) << 6) + lane], bf16u_to_f(u6));
            atomicAdd(&tile[((r7 >> 17) << 6) + lane], bf16u_to_f(u7));
        }
        for (; j < cnt; ++j) {
            unsigned int rv = (unsigned int)__shfl(rec, j);
            unsigned short u = Wtb[((size_t)(rv & 0x1FFFF) << 6) + lane];
            atomicAdd(&tile[((rv >> 17) << 6) + lane], bf16u_to_f(u));
        }
    }
    __syncthreads();
    int rmin = flags[1];
    int row0 = b * 256 - rmin;  // out row of tile row 0
    const float4* t4 = (const float4*)tile;
    float4* o4 = (float4*)out;
    for (int q = tid; q < 4096; q += 1024) {
        int lr = q >> 4;
        int orow = row0 + lr;
        if ((unsigned)orow < (unsigned)N) {
            float4 v = t4[q];
            int ch = (q & 15) << 2;
            v.x += bias[ch]; v.y += bias[ch + 1]; v.z += bias[ch + 2]; v.w += bias[ch + 3];
            o4[(size_t)orow * 16 + (q & 15)] = v;
        }
    }
}

// Bias for out rows [N-rmin, N) (uncovered when rmin > 0; usually no-op).
__global__ void LINK_biastail_kernel(float* __restrict__ out, const float* __restrict__ bias,
                                     const int* __restrict__ flags, int N) {
    int rmin = flags[1];
    if (rmin <= 0) return;
    if (rmin > N) rmin = N;
    long long total = (long long)rmin * 64;
    long long base = ((long long)N - rmin) * 64;
    long long i0 = (long long)blockIdx.x * blockDim.x + threadIdx.x;
    long long stride = (long long)gridDim.x * blockDim.x;
    for (long long i = i0; i < total; i += stride) out[base + i] = bias[(int)(i & 63)];
}

// Cleanup for spilled edges (expected zero on real data).
__global__ void LINK_ovf_kernel(const int* __restrict__ ovf, const int* __restrict__ flags,
                                const unsigned short* __restrict__ Wtb,
                                float* __restrict__ out, int N) {
    int g = blockIdx.x * blockDim.x + threadIdx.x;
    int w = g >> 6, lane = g & 63;
    int cnt = flags[8]; if (cnt > OVF_MAX) cnt = OVF_MAX;
    if (cnt == 0) return;
    int rmin = flags[1];
    int nw = (gridDim.x * blockDim.x) >> 6;
    for (int i = w; i < cnt; i += nw) {
        int r = ovf[2 * i] - rmin;
        int c = ovf[2 * i + 1];
        if ((unsigned)r >= (unsigned)N || (unsigned)c >= (unsigned)N) continue;
        atomicAdd(&out[((size_t)r << 6) + lane], bf16u_to_f(Wtb[((size_t)c << 6) + lane]));
    }
}

// ---- Fallback path (R6 analyze + R1 scatter) for unexpected shapes/ws ----
__global__ void LINK_initout_kernel(float* __restrict__ out, const float* __restrict__ b,
                                    int total, int* __restrict__ flags) {
    int i = blockIdx.x * blockDim.x + threadIdx.x;
    if (i == 0) { flags[0] = 0; flags[1] = 0x7fffffff; flags[2] = 0x7fffffff; }
    if (i < total) out[i] = b[i & 63];
}

__global__ __launch_bounds__(256) void LINK_analyze_kernel(
    const unsigned int* __restrict__ words, int E, int* __restrict__ flags) {
    const uint4* __restrict__ w4 = (const uint4*)words;
    int tid = blockIdx.x * blockDim.x + threadIdx.x;
    int nth = gridDim.x * blockDim.x;
    int n1 = E >> 2;
    long long twoE = 2LL * E;
    int n2 = (int)(twoE >> 2);
    unsigned int oddOr = 0u;
    int mn32 = 0x7fffffff, mn64 = 0x7fffffff;
    for (int i = tid; i < n2; i += nth) {
        uint4 w = w4[i];
        oddOr |= (w.y | w.w);
        mn64 = min(mn64, min((int)w.x, (int)w.z));
        if (i < n1)
            mn32 = min(mn32, min(min((int)w.x, (int)w.y), min((int)w.z, (int)w.w)));
    }
    for (long long i = ((long long)n1 << 2) + tid; i < E; i += nth)
        mn32 = min(mn32, (int)words[i]);
    for (long long i = ((long long)n2 << 2) + tid; i < twoE; i += nth) {
        unsigned int w = words[i];
        if (i & 1) oddOr |= w; else mn64 = min(mn64, (int)w);
    }
    for (int off = 32; off > 0; off >>= 1) {
        oddOr |= (unsigned int)__shfl_down((int)oddOr, off, 64);
        mn32 = min(mn32, __shfl_down(mn32, off, 64));
        mn64 = min(mn64, __shfl_down(mn64, off, 64));
    }
    __shared__ int s_or[4], s_m32[4], s_m64[4];
    int wid = threadIdx.x >> 6;
    if ((threadIdx.x & 63) == 0) { s_or[wid] = (int)oddOr; s_m32[wid] = mn32; s_m64[wid] = mn64; }
    __syncthreads();
    if (threadIdx.x == 0) {
        int o = s_or[0] | s_or[1] | s_or[2] | s_or[3];
        int a = min(min(s_m32[0], s_m32[1]), min(s_m32[2], s_m32[3]));
        int d = min(min(s_m64[0], s_m64[1]), min(s_m64[2], s_m64[3]));
        if (o) atomicOr(&flags[0], 1);
        atomicMin(&flags[1], a);
        atomicMin(&flags[2], d);
    }
}

__global__ void LINK_scatter_kernel(const unsigned int* __restrict__ words, int E,
                                    const float* __restrict__ W,
                                    float* __restrict__ out,
                                    const int* __restrict__ flags, int N) {
    long long g = (long long)blockIdx.x * blockDim.x + threadIdx.x;
    int e = (int)(g >> 6);
    if (e >= E) return;
    int ch = (int)(g & 63);
    int r, c, rmin;
    if (flags[0]) { r = (int)words[e]; c = (int)words[E + e]; rmin = flags[1]; }
    else { r = (int)words[2LL * e]; c = (int)words[2LL * (E + e)]; rmin = flags[2]; }
    r -= rmin;
    if ((unsigned)r >= (unsigned)N || (unsigned)c >= (unsigned)N) return;
    atomicAdd(&out[((size_t)r << 6) + ch], W[(size_t)ch * N + c]);
}

static inline size_t align256(size_t x) { return (x + 255) & ~(size_t)255; }

extern "C" void kernel_launch(void* const* d_in, const int* in_sizes, int n_in,
                              void* d_out, int out_size, void* d_ws, size_t ws_size,
                              hipStream_t stream) {
    const unsigned int* words = (const unsigned int*)d_in[0];
    const float* W = (const float*)d_in[1];
    const float* b = (const float*)d_in[2];
    float* out = (float*)d_out;

    int E = in_sizes[0] / 2;   // 3,200,000
    int N = in_sizes[1] / 64;  // 100,000
    int total = out_size;      // N*64
    int nbkt = (N + 255) / 256;  // 391

    size_t off_flags = 0;
    size_t off_wtb   = align256(off_flags + 256 * sizeof(int));
    size_t off_gtail = align256(off_wtb + (size_t)N * 64 * sizeof(unsigned short));
    size_t off_ovf   = align256(off_gtail + (size_t)NBKT_MAX * GT_STRIDE * sizeof(int));
    size_t off_recs  = align256(off_ovf + (size_t)OVF_MAX * 2 * sizeof(int));

    int* flags = (int*)((char*)d_ws + off_flags);
    unsigned short* Wtb = (unsigned short*)((char*)d_ws + off_wtb);
    int* gtail = (int*)((char*)d_ws + off_gtail);
    int* ovf   = (int*)((char*)d_ws + off_ovf);
    unsigned int* recs = (unsigned int*)((char*)d_ws + off_recs);

    long long avail = (ws_size > off_recs)
        ? (long long)((ws_size - off_recs) / ((size_t)nbkt * sizeof(int))) : 0;
    int segcap = (int)(avail > 16384 ? 16384 : avail);
    int avg = (int)((long long)E / (nbkt > 0 ? nbkt : 1)) + 1;
    bool useMain = (N <= (1 << 17)) && (nbkt <= NBKT_MAX) &&
                   (segcap >= avg + avg / 4 + SLOTS) && (E > 0);

    if (useMain) {
        LINK_detect_kernel<<<1, 1024, 0, stream>>>(words, E, flags, gtail, nbkt, segcap);
        LINK_transpose_kernel<<<(N + 63) / 64, 256, 0, stream>>>(W, Wtb, N);
        LINK_part_kernel<<<256, 1024, 0, stream>>>(words, E, N, nbkt, segcap,
                                                   gtail, recs, ovf, flags);
        LINK_accum_kernel<<<nbkt, 1024, 0, stream>>>(gtail, recs, segcap, Wtb, b,
                                                     out, flags, N);
        LINK_biastail_kernel<<<256, 256, 0, stream>>>(out, b, flags, N);
        LINK_ovf_kernel<<<64, 256, 0, stream>>>(ovf, flags, Wtb, out, N);
    } else {
        LINK_initout_kernel<<<(total + 255) / 256, 256, 0, stream>>>(out, b, total, flags);
        LINK_analyze_kernel<<<256, 256, 0, stream>>>(words, E, flags);
        long long tthreads = (long long)E * 64;
        LINK_scatter_kernel<<<(int)((tthreads + 255) / 256), 256, 0, stream>>>(
            words, E, W, out, flags, N);
    }
}

// Round 8
// 355.707 us; speedup vs baseline: 4.4132x; 4.4132x over previous
//
#include <hip/hip_runtime.h>

// out[r*64+ch] = b[ch] + sum_{edges (r,c)} W[ch][c],  r normalized by row.min().
// N = 100000, C = 64, E = 3.2M.
//
// R8: R6 pipeline (the 335us winner: XCD-sharded CSR fill + bf16 Wt row-gather)
//     with nontemporal cache policy: fill's edge reads NT (stop the read stream
//     evicting partially-filled cols lines from L2 — the measured 13x write
//     amplification), gather's cols reads NT + out stores NT (keep Wtb hot).
//     R3/R7 lesson: shfl-broadcast LDS-tile accum is latency-serialized (2x
//     measured ~1410us) — do NOT revisit that structure.
// ws: flags[256 int] | cur[N int] | Wtb[N*64 bf16] | ovf[OVF_MAX*2 int] | cols[N*64 int]

#define OVF_MAX (1 << 19)
#define CAP 64          // slots per row; Poisson(32) => P(overflow) ~ 1e-7 per row
#define NSHARD 8        // one shard per XCD (blockIdx % 8 round-robin heuristic)

typedef int v4i __attribute__((ext_vector_type(4)));

__device__ __forceinline__ float bf16u_to_f(unsigned short u) {
    union { unsigned int i; float f; } x; x.i = ((unsigned int)u) << 16; return x.f;
}

__global__ void LINK_init_kernel(int* __restrict__ cur, int* __restrict__ flags, int N) {
    int i = blockIdx.x * blockDim.x + threadIdx.x;
    if (i == 0) { flags[0] = 0; flags[1] = 0x7fffffff; flags[2] = 0x7fffffff; flags[8] = 0; }
    if (i < N) cur[i] = i << 6;  // i * CAP
}

// Full scan of words[0..2E): oddOr (dtype detect), mn64 (even words),
// mn32 (words[0..E)). One atomic triple per block (R5 lesson: same-line
// atomics serialize at ~12ns each).
__global__ __launch_bounds__(256) void LINK_analyze_kernel(
    const unsigned int* __restrict__ words, int E, int* __restrict__ flags) {
    const uint4* __restrict__ w4 = (const uint4*)words;
    int tid = blockIdx.x * blockDim.x + threadIdx.x;
    int nth = gridDim.x * blockDim.x;
    int n1 = E >> 2;            // uint4s fully inside [0, E)
    long long twoE = 2LL * E;
    int n2 = (int)(twoE >> 2);  // uint4s fully inside [0, 2E)
    unsigned int oddOr = 0u;
    int mn32 = 0x7fffffff, mn64 = 0x7fffffff;
    {
        int i = tid;
        for (; i + 3 * nth < n1; i += 4 * nth) {
            uint4 a = w4[i], b = w4[i + nth], c = w4[i + 2 * nth], d = w4[i + 3 * nth];
            oddOr |= (a.y | a.w) | (b.y | b.w) | (c.y | c.w) | (d.y | d.w);
            int m1 = min(min((int)a.x, (int)a.z), min((int)b.x, (int)b.z));
            int m2 = min(min((int)c.x, (int)c.z), min((int)d.x, (int)d.z));
            mn64 = min(mn64, min(m1, m2));
            int p1 = min(min((int)a.x, (int)a.y), min((int)a.z, (int)a.w));
            int p2 = min(min((int)b.x, (int)b.y), min((int)b.z, (int)b.w));
            int p3 = min(min((int)c.x, (int)c.y), min((int)c.z, (int)c.w));
            int p4 = min(min((int)d.x, (int)d.y), min((int)d.z, (int)d.w));
            mn32 = min(mn32, min(min(p1, p2), min(p3, p4)));
        }
        for (; i < n1; i += nth) {
            uint4 a = w4[i];
            oddOr |= (a.y | a.w);
            mn64 = min(mn64, min((int)a.x, (int)a.z));
            mn32 = min(mn32, min(min((int)a.x, (int)a.y), min((int)a.z, (int)a.w)));
        }
    }
    {
        int i = n1 + tid;
        for (; i + 3 * nth < n2; i += 4 * nth) {
            uint4 a = w4[i], b = w4[i + nth], c = w4[i + 2 * nth], d = w4[i + 3 * nth];
            oddOr |= (a.y | a.w) | (b.y | b.w) | (c.y | c.w) | (d.y | d.w);
            int m1 = min(min((int)a.x, (int)a.z), min((int)b.x, (int)b.z));
            int m2 = min(min((int)c.x, (int)c.z), min((int)d.x, (int)d.z));
            mn64 = min(mn64, min(m1, m2));
        }
        for (; i < n2; i += nth) {
            uint4 a = w4[i];
            oddOr |= (a.y | a.w);
            mn64 = min(mn64, min((int)a.x, (int)a.z));
        }
    }
    for (long long i = ((long long)n1 << 2) + tid; i < E; i += nth)
        mn32 = min(mn32, (int)words[i]);
    for (long long i = ((long long)n2 << 2) + tid; i < twoE; i += nth) {
        unsigned int w = words[i];
        if (i & 1) oddOr |= w; else mn64 = min(mn64, (int)w);
    }
    for (int off = 32; off > 0; off >>= 1) {
        oddOr |= (unsigned int)__shfl_down((int)oddOr, off, 64);
        mn32 = min(mn32, __shfl_down(mn32, off, 64));
        mn64 = min(mn64, __shfl_down(mn64, off, 64));
    }
    __shared__ int s_or[4], s_m32[4], s_m64[4];
    int wid = threadIdx.x >> 6;
    if ((threadIdx.x & 63) == 0) {
        s_or[wid] = (int)oddOr; s_m32[wid] = mn32; s_m64[wid] = mn64;
    }
    __syncthreads();
    if (threadIdx.x == 0) {
        int o = s_or[0] | s_or[1] | s_or[2] | s_or[3];
        int a = min(min(s_m32[0], s_m32[1]), min(s_m32[2], s_m32[3]));
        int d = min(min(s_m64[0], s_m64[1]), min(s_m64[2], s_m64[3]));
        if (o) atomicOr(&flags[0], 1);
        atomicMin(&flags[1], a);
        atomicMin(&flags[2], d);
    }
}

// W [64][N] f32 -> Wtb [N][64] bf16 (RNE) via padded LDS tile.
__global__ void LINK_transpose_kernel(const float* __restrict__ W,
                                      unsigned short* __restrict__ Wtb, int N) {
    __shared__ float tile[64][65];
    int n0 = blockIdx.x * 64;
    int lx = threadIdx.x & 63;
    int ly = threadIdx.x >> 6;
#pragma unroll
    for (int it = 0; it < 16; ++it) {
        int ch = ly + 4 * it;
        float v = 0.0f;
        if (n0 + lx < N) v = W[(size_t)ch * N + (n0 + lx)];
        tile[lx][ch] = v;
    }
    __syncthreads();
#pragma unroll
    for (int it = 0; it < 16; ++it) {
        int nn = ly + 4 * it;
        if (n0 + nn < N) {
            union { float f; unsigned int i; } x; x.f = tile[nn][lx];
            unsigned int u = x.i;
            unsigned int r = (u + 0x7fffu + ((u >> 16) & 1u)) >> 16;  // RNE
            Wtb[((size_t)(n0 + nn) << 6) + lx] = (unsigned short)r;
        }
    }
}

// XCD-sharded CSR fill: block b owns row shard (b & 7); shard cols region
// (12500 rows * 64 slots * 4B = 3.2MB) targets one XCD's L2. Edge reads are
// NONTEMPORAL so the read stream doesn't evict partially-filled cols lines
// (R6 measured 170MB WRITE = 13x amplification without this).
__global__ __launch_bounds__(256) void LINK_fill_kernel(
    const unsigned int* __restrict__ words, int E, int N,
    int* __restrict__ cur, int* __restrict__ cols,
    int* __restrict__ ovf, int* __restrict__ flags) {
    int shard = blockIdx.x & (NSHARD - 1);
    int qb = blockIdx.x >> 3;
    int Q = gridDim.x >> 3;
    int rows_per = (N + NSHARD - 1) / NSHARD;
    int rlo = shard * rows_per;
    int rhi = min(N, rlo + rows_per);
    int isInt32 = flags[0];
    long long i0 = (long long)qb * blockDim.x + threadIdx.x;
    long long stride = (long long)Q * blockDim.x;
    for (long long e = i0; e < E; e += stride) {
        int r = isInt32 ? (int)__builtin_nontemporal_load(words + e)
                        : (int)__builtin_nontemporal_load(words + 2 * e);
        if (r < rlo || r >= rhi) continue;
        int c = isInt32 ? (int)__builtin_nontemporal_load(words + E + e)
                        : (int)__builtin_nontemporal_load(words + 2LL * E + 2 * e);
        if ((unsigned)c >= (unsigned)N) continue;
        int pos = atomicAdd(&cur[r], 1);
        if (pos - (r << 6) < CAP) {
            cols[pos] = c;
        } else {
            int oi = atomicAdd(&flags[8], 1);
            if (oi < OVF_MAX) { ovf[2 * oi] = r; ovf[2 * oi + 1] = c; }
        }
    }
}

// One wave per output row; lane = channel. bf16 Wt rows (128B coalesced), fp32 acc,
// 8 independent Wtb loads in flight; cols read NT (stream-once), out stored NT —
// keeps Wtb (the only reused array) resident in L2.
__global__ __launch_bounds__(256) void LINK_gather_kernel(
    const int* __restrict__ cur, const int* __restrict__ cols,
    const unsigned short* __restrict__ Wtb, const float* __restrict__ b,
    float* __restrict__ out, const int* __restrict__ flags, int N) {
    int g = blockIdx.x * blockDim.x + threadIdx.x;
    int row = g >> 6;
    int lane = g & 63;
    if (row >= N) return;
    int rmin = flags[0] ? flags[1] : flags[2];
    float acc = 0.0f;
    long long raw = (long long)row + rmin;
    if (raw >= 0 && raw < N) {
        int base = (int)raw << 6;
        int len = cur[raw] - base;
        if (len > CAP) len = CAP;
        const v4i* cp4 = (const v4i*)(cols + base);  // 256B-aligned
        int j = 0;
        for (; j + 8 <= len; j += 8) {
            v4i q0 = __builtin_nontemporal_load(cp4 + (j >> 2));
            v4i q1 = __builtin_nontemporal_load(cp4 + (j >> 2) + 1);
            unsigned short u0 = Wtb[((size_t)q0.x << 6) + lane];
            unsigned short u1 = Wtb[((size_t)q0.y << 6) + lane];
            unsigned short u2 = Wtb[((size_t)q0.z << 6) + lane];
            unsigned short u3 = Wtb[((size_t)q0.w << 6) + lane];
            unsigned short u4 = Wtb[((size_t)q1.x << 6) + lane];
            unsigned short u5 = Wtb[((size_t)q1.y << 6) + lane];
            unsigned short u6 = Wtb[((size_t)q1.z << 6) + lane];
            unsigned short u7 = Wtb[((size_t)q1.w << 6) + lane];
            float s01 = bf16u_to_f(u0) + bf16u_to_f(u1);
            float s23 = bf16u_to_f(u2) + bf16u_to_f(u3);
            float s45 = bf16u_to_f(u4) + bf16u_to_f(u5);
            float s67 = bf16u_to_f(u6) + bf16u_to_f(u7);
            acc += (s01 + s23) + (s45 + s67);
        }
        const int* cp = cols + base;
        for (; j < len; ++j)
            acc += bf16u_to_f(Wtb[((size_t)cp[j] << 6) + lane]);
    }
    __builtin_nontemporal_store(acc + b[lane], &out[((size_t)row << 6) + lane]);
}

// Cleanup for spilled edges (expected zero on real data).
__global__ void LINK_ovf_kernel(const int* __restrict__ ovf, const int* __restrict__ flags,
                                const unsigned short* __restrict__ Wtb,
                                float* __restrict__ out, int N) {
    int g = blockIdx.x * blockDim.x + threadIdx.x;
    int w = g >> 6, lane = g & 63;
    int cnt = flags[8]; if (cnt > OVF_MAX) cnt = OVF_MAX;
    if (cnt == 0) return;
    int rmin = flags[0] ? flags[1] : flags[2];
    int nw = (gridDim.x * blockDim.x) >> 6;
    for (int i = w; i < cnt; i += nw) {
        int r = ovf[2 * i] - rmin;
        int c = ovf[2 * i + 1];
        if ((unsigned)r >= (unsigned)N || (unsigned)c >= (unsigned)N) continue;
        atomicAdd(&out[((size_t)r << 6) + lane], bf16u_to_f(Wtb[((size_t)c << 6) + lane]));
    }
}

// ---- Fallback (R1): bias init + wave-per-edge fp-atomic scatter on raw W ----
__global__ void LINK_initout_kernel(float* __restrict__ out, const float* __restrict__ b,
                                    int total, int* __restrict__ flags) {
    int i = blockIdx.x * blockDim.x + threadIdx.x;
    if (i == 0) { flags[0] = 0; flags[1] = 0x7fffffff; flags[2] = 0x7fffffff; }
    if (i < total) out[i] = b[i & 63];
}

__global__ void LINK_scatter_kernel(const unsigned int* __restrict__ words, int E,
                                    const float* __restrict__ W,
                                    float* __restrict__ out,
                                    const int* __restrict__ flags, int N) {
    long long g = (long long)blockIdx.x * blockDim.x + threadIdx.x;
    int e = (int)(g >> 6);
    if (e >= E) return;
    int ch = (int)(g & 63);
    int r, c, rmin;
    if (flags[0]) { r = (int)words[e]; c = (int)words[E + e]; rmin = flags[1]; }
    else { r = (int)words[2LL * e]; c = (int)words[2LL * (E + e)]; rmin = flags[2]; }
    r -= rmin;
    if ((unsigned)r >= (unsigned)N || (unsigned)c >= (unsigned)N) return;
    atomicAdd(&out[((size_t)r << 6) + ch], W[(size_t)ch * N + c]);
}

static inline size_t align256(size_t x) { return (x + 255) & ~(size_t)255; }

extern "C" void kernel_launch(void* const* d_in, const int* in_sizes, int n_in,
                              void* d_out, int out_size, void* d_ws, size_t ws_size,
                              hipStream_t stream) {
    const unsigned int* words = (const unsigned int*)d_in[0];
    const float* W = (const float*)d_in[1];
    const float* b = (const float*)d_in[2];
    float* out = (float*)d_out;

    int E = in_sizes[0] / 2;   // 3,200,000
    int N = in_sizes[1] / 64;  // 100,000
    int total = out_size;      // N*64

    size_t off_flags = 0;
    size_t off_cur   = align256(off_flags + 256 * sizeof(int));
    size_t off_wtb   = align256(off_cur + (size_t)N * sizeof(int));
    size_t off_ovf   = align256(off_wtb + (size_t)N * 64 * sizeof(unsigned short));
    size_t off_cols  = align256(off_ovf + (size_t)OVF_MAX * 2 * sizeof(int));
    size_t need      = off_cols + (size_t)N * CAP * sizeof(int);

    int* flags = (int*)((char*)d_ws + off_flags);
    int* cur   = (int*)((char*)d_ws + off_cur);
    unsigned short* Wtb = (unsigned short*)((char*)d_ws + off_wtb);
    int* ovf   = (int*)((char*)d_ws + off_ovf);
    int* cols  = (int*)((char*)d_ws + off_cols);

    if (ws_size >= need) {
        LINK_init_kernel<<<(N + 255) / 256, 256, 0, stream>>>(cur, flags, N);
        LINK_analyze_kernel<<<256, 256, 0, stream>>>(words, E, flags);
        LINK_transpose_kernel<<<(N + 63) / 64, 256, 0, stream>>>(W, Wtb, N);
        LINK_fill_kernel<<<2048, 256, 0, stream>>>(words, E, N, cur, cols, ovf, flags);
        long long gthreads = (long long)N * 64;
        LINK_gather_kernel<<<(int)((gthreads + 255) / 256), 256, 0, stream>>>(
            cur, cols, Wtb, b, out, flags, N);
        LINK_ovf_kernel<<<64, 256, 0, stream>>>(ovf, flags, Wtb, out, N);
    } else {
        LINK_initout_kernel<<<(total + 255) / 256, 256, 0, stream>>>(out, b, total, flags);
        LINK_analyze_kernel<<<256, 256, 0, stream>>>(words, E, flags);
        long long tthreads = (long long)E * 64;
        LINK_scatter_kernel<<<(int)((tthreads + 255) / 256), 256, 0, stream>>>(
            words, E, W, out, flags, N);
    }
}

// Round 9
// 247.216 us; speedup vs baseline: 6.3499x; 1.4389x over previous
//
#include <hip/hip_runtime.h>

// out[r*64+ch] = b[ch] + sum_{edges (r,c)} W[ch][c],  r normalized by row.min().
// N = 100000, C = 64, E = 3.2M.
//
// R9: two-phase bucket pipeline. partition: edges -> 391 buckets of 256 rows,
//     4B records (lrow<<17|col), LDS-staged coalesced flushes (edges read ONCE,
//     records written coalesced — kills fill's 100MB re-read + 132MB scattered-
//     write amplification). bucket-gather: per-bucket block bins col-ids into
//     per-row LDS lists (LDS atomics), then runs the PROVEN R6 row-gather inner
//     loop (lane=channel, 8-deep independent 128B bf16-Wt loads) from LDS lists.
//     R3/R7 lesson (twice measured ~1410us): NO shfl-broadcast-per-record accum.
//     R5 lesson: no same-cache-line global atomics (gtail padded to 64B).
// ws: flags | Wtb[N*64 bf16] | gtail[nbkt*16] | ovf | recs[nbkt*segcap]

#define OVF_MAX (1 << 19)
#define NBKT_MAX 400
#define SLOTS 36
#define FLUSH_T 24
#define GT_STRIDE 16
#define SL 64           // LDS col-list slots per row; P(Poisson(32)>64) ~ 3e-7

__device__ __forceinline__ float bf16u_to_f(unsigned short u) {
    union { unsigned int i; float f; } x; x.i = ((unsigned int)u) << 16; return x.f;
}

// 1 block: dtype probe (head+tail odd words) + flags/gtail init.
__global__ __launch_bounds__(1024) void LINK_detect_kernel(
    const unsigned int* __restrict__ words, int E, int* __restrict__ flags,
    int* __restrict__ gtail, int nbkt, int segcap) {
    long long twoE = 2LL * E;
    int tid = threadIdx.x;
    unsigned int oddOr = 0u;
    int nscan = (int)(twoE < 8192 ? twoE : 8192);
    for (int i = tid; i < nscan; i += blockDim.x) {
        if (i & 1) oddOr |= words[i];
        long long j = twoE - 1 - i;
        if (j >= nscan && (j & 1)) oddOr |= words[j];
    }
    __shared__ unsigned int sred[16];
    for (int off = 32; off > 0; off >>= 1)
        oddOr |= (unsigned int)__shfl_down((int)oddOr, off, 64);
    int wid = tid >> 6;
    if ((tid & 63) == 0) sred[wid] = oddOr;
    __syncthreads();
    if (tid == 0) {
        unsigned int o = 0;
        for (int i = 0; i < (int)(blockDim.x >> 6); ++i) o |= sred[i];
        flags[0] = o ? 1 : 0;   // 1 = int32 layout
        flags[1] = 0x7fffffff;  // rmin (partition fills via atomicMin)
        flags[8] = 0;           // ovf count
    }
    for (int k = tid; k < nbkt; k += blockDim.x) gtail[k * GT_STRIDE] = k * segcap;
}

// W [64][N] f32 -> Wtb [N][64] bf16 (RNE) via padded LDS tile.
__global__ void LINK_transpose_kernel(const float* __restrict__ W,
                                      unsigned short* __restrict__ Wtb, int N) {
    __shared__ float tile[64][65];
    int n0 = blockIdx.x * 64;
    int lx = threadIdx.x & 63;
    int ly = threadIdx.x >> 6;
#pragma unroll
    for (int it = 0; it < 16; ++it) {
        int ch = ly + 4 * it;
        float v = 0.0f;
        if (n0 + lx < N) v = W[(size_t)ch * N + (n0 + lx)];
        tile[lx][ch] = v;
    }
    __syncthreads();
#pragma unroll
    for (int it = 0; it < 16; ++it) {
        int nn = ly + 4 * it;
        if (n0 + nn < N) {
            union { float f; unsigned int i; } x; x.f = tile[nn][lx];
            unsigned int u = x.i;
            unsigned int r = (u + 0x7fffu + ((u >> 16) & 1u)) >> 16;  // RNE
            Wtb[((size_t)(n0 + nn) << 6) + lx] = (unsigned short)r;
        }
    }
}

// Edges -> 256-row buckets. Records 4B: (r&255)<<17 | c. LDS-staged, wave-wide
// coalesced flushes. Also block-reduces rmin -> atomicMin(flags[1]).
__global__ __launch_bounds__(1024) void LINK_part_kernel(
    const unsigned int* __restrict__ words, int E, int N, int nbkt, int segcap,
    int* __restrict__ gtail, unsigned int* __restrict__ recs,
    int* __restrict__ ovf, int* __restrict__ flags) {
    __shared__ unsigned int lstage[NBKT_MAX * SLOTS];  // 57.6 KB
    __shared__ int lcnt[NBKT_MAX];
    __shared__ int sred[16];
    int tid = threadIdx.x;
    for (int k = tid; k < nbkt; k += blockDim.x) lcnt[k] = 0;
    __syncthreads();
    int isInt32 = flags[0];
    int mnr = 0x7fffffff;
    int nblk = gridDim.x;
    long long per_round = (long long)nblk * blockDim.x;
    long long nround = ((long long)E + per_round - 1) / per_round;
    int lane = tid & 63, wid = tid >> 6, nw = blockDim.x >> 6;
    for (long long rd = 0; rd < nround; ++rd) {
        long long e = (rd * nblk + blockIdx.x) * blockDim.x + tid;
        if (e < E) {
            int r, c;
            if (isInt32) { r = (int)words[e]; c = (int)words[E + e]; }
            else { r = (int)words[2 * e]; c = (int)words[2LL * E + 2 * e]; }
            mnr = min(mnr, r);
            if ((unsigned)r < (unsigned)N && (unsigned)c < (unsigned)N) {
                int k = r >> 8;
                unsigned int rec = ((unsigned int)(r & 255) << 17) | (unsigned int)c;
                int pos = atomicAdd(&lcnt[k], 1);
                if (pos < SLOTS) {
                    lstage[k * SLOTS + pos] = rec;
                } else {  // rare mid-round spill: direct global append
                    int g = atomicAdd(&gtail[k * GT_STRIDE], 1);
                    if (g < (k + 1) * segcap) recs[g] = rec;
                    else {
                        int oi = atomicAdd(&flags[8], 1);
                        if (oi < OVF_MAX) { ovf[2 * oi] = r; ovf[2 * oi + 1] = c; }
                    }
                }
            }
        }
        __syncthreads();
        bool last = (rd == nround - 1);
        for (int k = wid; k < nbkt; k += nw) {
            int cnt = lcnt[k]; if (cnt > SLOTS) cnt = SLOTS;
            if (cnt >= FLUSH_T || (last && cnt > 0)) {
                int g = 0;
                if (lane == 0) g = atomicAdd(&gtail[k * GT_STRIDE], cnt);
                g = __shfl(g, 0);
                if (lane < cnt) {
                    int gg = g + lane;
                    unsigned int rec = lstage[k * SLOTS + lane];
                    if (gg < (k + 1) * segcap) recs[gg] = rec;
                    else {
                        int oi = atomicAdd(&flags[8], 1);
                        if (oi < OVF_MAX) {
                            ovf[2 * oi] = (k << 8) | (int)(rec >> 17);
                            ovf[2 * oi + 1] = (int)(rec & 0x1FFFF);
                        }
                    }
                }
                if (lane == 0) lcnt[k] = 0;
            }
        }
        __syncthreads();
    }
    for (int off = 32; off > 0; off >>= 1) mnr = min(mnr, __shfl_down(mnr, off, 64));
    if (lane == 0) sred[wid] = mnr;
    __syncthreads();
    if (tid == 0) {
        int m = 0x7fffffff;
        for (int i = 0; i < 16; ++i) m = min(m, sred[i]);
        atomicMin(&flags[1], m);
    }
}

// One block per bucket. Phase 1: bin the bucket's records into per-row LDS col
// lists (LDS atomics — no global write amplification). Phase 2: R6-style
// row-gather — wave per row, lane=channel, 8 independent 128B Wtb loads in
// flight, one coalesced bias+store per row.
__global__ __launch_bounds__(1024) void LINK_bgather_kernel(
    const int* __restrict__ gtail, const unsigned int* __restrict__ recs, int segcap,
    const unsigned short* __restrict__ Wtb, const float* __restrict__ bias,
    float* __restrict__ out, int* __restrict__ flags, int* __restrict__ ovf, int N) {
    __shared__ int lcols[256 * SL];  // 64 KB
    __shared__ int lcnt[256];
    int b = blockIdx.x, tid = threadIdx.x;
    for (int i = tid; i < 256; i += 1024) lcnt[i] = 0;
    __syncthreads();
    int len = gtail[b * GT_STRIDE] - b * segcap;
    if (len > segcap) len = segcap;
    if (len < 0) len = 0;
    const unsigned int* rp = recs + (size_t)b * segcap;
    for (int i = tid; i < len; i += 1024) {
        unsigned int rec = rp[i];
        int lr = (int)(rec >> 17);
        int c = (int)(rec & 0x1FFFF);
        int pos = atomicAdd(&lcnt[lr], 1);
        if (pos < SL) {
            lcols[(lr << 6) + pos] = c;
        } else {  // astronomically rare: defer to global ovf cleanup
            int oi = atomicAdd(&flags[8], 1);
            if (oi < OVF_MAX) { ovf[2 * oi] = (b << 8) | lr; ovf[2 * oi + 1] = c; }
        }
    }
    __syncthreads();
    int rmin = flags[1];
    int lane = tid & 63, wid = tid >> 6;
    for (int lr = wid; lr < 256; lr += 16) {
        int cnt = lcnt[lr]; if (cnt > SL) cnt = SL;
        int base = lr << 6;
        float acc = 0.0f;
        int j = 0;
        for (; j + 8 <= cnt; j += 8) {
            int c0 = lcols[base + j + 0], c1 = lcols[base + j + 1];
            int c2 = lcols[base + j + 2], c3 = lcols[base + j + 3];
            int c4 = lcols[base + j + 4], c5 = lcols[base + j + 5];
            int c6 = lcols[base + j + 6], c7 = lcols[base + j + 7];
            unsigned short u0 = Wtb[((size_t)c0 << 6) + lane];
            unsigned short u1 = Wtb[((size_t)c1 << 6) + lane];
            unsigned short u2 = Wtb[((size_t)c2 << 6) + lane];
            unsigned short u3 = Wtb[((size_t)c3 << 6) + lane];
            unsigned short u4 = Wtb[((size_t)c4 << 6) + lane];
            unsigned short u5 = Wtb[((size_t)c5 << 6) + lane];
            unsigned short u6 = Wtb[((size_t)c6 << 6) + lane];
            unsigned short u7 = Wtb[((size_t)c7 << 6) + lane];
            float s01 = bf16u_to_f(u0) + bf16u_to_f(u1);
            float s23 = bf16u_to_f(u2) + bf16u_to_f(u3);
            float s45 = bf16u_to_f(u4) + bf16u_to_f(u5);
            float s67 = bf16u_to_f(u6) + bf16u_to_f(u7);
            acc += (s01 + s23) + (s45 + s67);
        }
        for (; j < cnt; ++j)
            acc += bf16u_to_f(Wtb[((size_t)lcols[base + j] << 6) + lane]);
        int orow = b * 256 + lr - rmin;
        if ((unsigned)orow < (unsigned)N)
            out[((size_t)orow << 6) + lane] = acc + bias[lane];
    }
}

// Bias for out rows not covered by any bucket (only when rmin large; usually no-op).
__global__ void LINK_biastail_kernel(float* __restrict__ out, const float* __restrict__ bias,
                                     const int* __restrict__ flags, int N, int nbkt) {
    int rmin = flags[1];
    long long start = (long long)nbkt * 256 - (long long)rmin;
    if (start < 0) start = 0;
    if (start >= N) return;
    long long total = ((long long)N - start) * 64;
    long long base = start * 64;
    long long i0 = (long long)blockIdx.x * blockDim.x + threadIdx.x;
    long long stride = (long long)gridDim.x * blockDim.x;
    for (long long i = i0; i < total; i += stride) out[base + i] = bias[(int)(i & 63)];
}

// Cleanup for spilled edges (expected zero on real data). ovf[2i] = raw row.
__global__ void LINK_ovf_kernel(const int* __restrict__ ovf, const int* __restrict__ flags,
                                const unsigned short* __restrict__ Wtb,
                                float* __restrict__ out, int N) {
    int g = blockIdx.x * blockDim.x + threadIdx.x;
    int w = g >> 6, lane = g & 63;
    int cnt = flags[8]; if (cnt > OVF_MAX) cnt = OVF_MAX;
    if (cnt == 0) return;
    int rmin = flags[1];
    int nw = (gridDim.x * blockDim.x) >> 6;
    for (int i = w; i < cnt; i += nw) {
        int r = ovf[2 * i] - rmin;
        int c = ovf[2 * i + 1];
        if ((unsigned)r >= (unsigned)N || (unsigned)c >= (unsigned)N) continue;
        atomicAdd(&out[((size_t)r << 6) + lane], bf16u_to_f(Wtb[((size_t)c << 6) + lane]));
    }
}

// ---- Fallback path for unexpected shapes/ws: analyze + bias init + scatter ----
__global__ void LINK_initout_kernel(float* __restrict__ out, const float* __restrict__ b,
                                    int total, int* __restrict__ flags) {
    int i = blockIdx.x * blockDim.x + threadIdx.x;
    if (i == 0) { flags[0] = 0; flags[1] = 0x7fffffff; flags[2] = 0x7fffffff; }
    if (i < total) out[i] = b[i & 63];
}

__global__ __launch_bounds__(256) void LINK_analyze_kernel(
    const unsigned int* __restrict__ words, int E, int* __restrict__ flags) {
    const uint4* __restrict__ w4 = (const uint4*)words;
    int tid = blockIdx.x * blockDim.x + threadIdx.x;
    int nth = gridDim.x * blockDim.x;
    int n1 = E >> 2;
    long long twoE = 2LL * E;
    int n2 = (int)(twoE >> 2);
    unsigned int oddOr = 0u;
    int mn32 = 0x7fffffff, mn64 = 0x7fffffff;
    for (int i = tid; i < n2; i += nth) {
        uint4 w = w4[i];
        oddOr |= (w.y | w.w);
        mn64 = min(mn64, min((int)w.x, (int)w.z));
        if (i < n1)
            mn32 = min(mn32, min(min((int)w.x, (int)w.y), min((int)w.z, (int)w.w)));
    }
    for (long long i = ((long long)n1 << 2) + tid; i < E; i += nth)
        mn32 = min(mn32, (int)words[i]);
    for (long long i = ((long long)n2 << 2) + tid; i < twoE; i += nth) {
        unsigned int w = words[i];
        if (i & 1) oddOr |= w; else mn64 = min(mn64, (int)w);
    }
    for (int off = 32; off > 0; off >>= 1) {
        oddOr |= (unsigned int)__shfl_down((int)oddOr, off, 64);
        mn32 = min(mn32, __shfl_down(mn32, off, 64));
        mn64 = min(mn64, __shfl_down(mn64, off, 64));
    }
    __shared__ int s_or[4], s_m32[4], s_m64[4];
    int wid = threadIdx.x >> 6;
    if ((threadIdx.x & 63) == 0) { s_or[wid] = (int)oddOr; s_m32[wid] = mn32; s_m64[wid] = mn64; }
    __syncthreads();
    if (threadIdx.x == 0) {
        int o = s_or[0] | s_or[1] | s_or[2] | s_or[3];
        int a = min(min(s_m32[0], s_m32[1]), min(s_m32[2], s_m32[3]));
        int d = min(min(s_m64[0], s_m64[1]), min(s_m64[2], s_m64[3]));
        if (o) atomicOr(&flags[0], 1);
        atomicMin(&flags[1], a);
        atomicMin(&flags[2], d);
    }
}

__global__ void LINK_scatter_kernel(const unsigned int* __restrict__ words, int E,
                                    const float* __restrict__ W,
                                    float* __restrict__ out,
                                    const int* __restrict__ flags, int N) {
    long long g = (long long)blockIdx.x * blockDim.x + threadIdx.x;
    int e = (int)(g >> 6);
    if (e >= E) return;
    int ch = (int)(g & 63);
    int r, c, rmin;
    if (flags[0]) { r = (int)words[e]; c = (int)words[E + e]; rmin = flags[1]; }
    else { r = (int)words[2LL * e]; c = (int)words[2LL * (E + e)]; rmin = flags[2]; }
    r -= rmin;
    if ((unsigned)r >= (unsigned)N || (unsigned)c >= (unsigned)N) return;
    atomicAdd(&out[((size_t)r << 6) + ch], W[(size_t)ch * N + c]);
}

static inline size_t align256(size_t x) { return (x + 255) & ~(size_t)255; }

extern "C" void kernel_launch(void* const* d_in, const int* in_sizes, int n_in,
                              void* d_out, int out_size, void* d_ws, size_t ws_size,
                              hipStream_t stream) {
    const unsigned int* words = (const unsigned int*)d_in[0];
    const float* W = (const float*)d_in[1];
    const float* b = (const float*)d_in[2];
    float* out = (float*)d_out;

    int E = in_sizes[0] / 2;   // 3,200,000
    int N = in_sizes[1] / 64;  // 100,000
    int total = out_size;      // N*64
    int nbkt = (N + 255) / 256;  // 391

    size_t off_flags = 0;
    size_t off_wtb   = align256(off_flags + 256 * sizeof(int));
    size_t off_gtail = align256(off_wtb + (size_t)N * 64 * sizeof(unsigned short));
    size_t off_ovf   = align256(off_gtail + (size_t)NBKT_MAX * GT_STRIDE * sizeof(int));
    size_t off_recs  = align256(off_ovf + (size_t)OVF_MAX * 2 * sizeof(int));

    int* flags = (int*)((char*)d_ws + off_flags);
    unsigned short* Wtb = (unsigned short*)((char*)d_ws + off_wtb);
    int* gtail = (int*)((char*)d_ws + off_gtail);
    int* ovf   = (int*)((char*)d_ws + off_ovf);
    unsigned int* recs = (unsigned int*)((char*)d_ws + off_recs);

    long long avail = (ws_size > off_recs)
        ? (long long)((ws_size - off_recs) / ((size_t)nbkt * sizeof(int))) : 0;
    int segcap = (int)(avail > 16384 ? 16384 : avail);
    int avg = (int)((long long)E / (nbkt > 0 ? nbkt : 1)) + 1;
    bool useMain = (N <= (1 << 17)) && (nbkt <= NBKT_MAX) &&
                   (segcap >= avg + avg / 4 + SLOTS) && (E > 0);

    if (useMain) {
        LINK_detect_kernel<<<1, 1024, 0, stream>>>(words, E, flags, gtail, nbkt, segcap);
        LINK_transpose_kernel<<<(N + 63) / 64, 256, 0, stream>>>(W, Wtb, N);
        LINK_part_kernel<<<256, 1024, 0, stream>>>(words, E, N, nbkt, segcap,
                                                   gtail, recs, ovf, flags);
        LINK_bgather_kernel<<<nbkt, 1024, 0, stream>>>(gtail, recs, segcap, Wtb, b,
                                                       out, flags, ovf, N);
        LINK_biastail_kernel<<<64, 256, 0, stream>>>(out, b, flags, N, nbkt);
        LINK_ovf_kernel<<<64, 256, 0, stream>>>(ovf, flags, Wtb, out, N);
    } else {
        LINK_initout_kernel<<<(total + 255) / 256, 256, 0, stream>>>(out, b, total, flags);
        LINK_analyze_kernel<<<256, 256, 0, stream>>>(words, E, flags);
        long long tthreads = (long long)E * 64;
        LINK_scatter_kernel<<<(int)((tthreads + 255) / 256), 256, 0, stream>>>(
            words, E, W, out, flags, N);
    }
}

// Round 10
// 228.904 us; speedup vs baseline: 6.8579x; 1.0800x over previous
//
#include <hip/hip_runtime.h>

// out[r*64+ch] = b[ch] + sum_{edges (r,c)} W[ch][c],  r normalized by row.min().
// N = 100000, C = 64, E = 3.2M.
//
// R10: R9 pipeline with occupancy fixes.
//  - bgather: 2 sub-blocks per bucket (128 rows each, 512 thr, 32.5KB LDS ->
//    4 blocks/CU = full 32-wave occupancy; tail quantum halved). R9 measured
//    51% occupancy from 391x65KB blocks (1.53 blocks/CU + tail round).
//  - partition: grid 512 (2 blocks/CU), NT edge loads.
//  Lessons kept: no shfl-broadcast-per-record accum (R3/R7: ~1410us twice);
//  no same-line global atomics (R5: ~12ns each, serial); row-gather inner loop
//  with 8 independent 128B bf16 loads is the proven fast structure (R6/R9).
// ws: flags | Wtb[N*64 bf16] | gtail[nbkt*16] | ovf | recs[nbkt*segcap]

#define OVF_MAX (1 << 19)
#define NBKT_MAX 400
#define SLOTS 36
#define FLUSH_T 24
#define GT_STRIDE 16
#define SL 64           // LDS col-list slots per row

__device__ __forceinline__ float bf16u_to_f(unsigned short u) {
    union { unsigned int i; float f; } x; x.i = ((unsigned int)u) << 16; return x.f;
}

// 1 block: dtype probe (head+tail odd words) + flags/gtail init.
__global__ __launch_bounds__(1024) void LINK_detect_kernel(
    const unsigned int* __restrict__ words, int E, int* __restrict__ flags,
    int* __restrict__ gtail, int nbkt, int segcap) {
    long long twoE = 2LL * E;
    int tid = threadIdx.x;
    unsigned int oddOr = 0u;
    int nscan = (int)(twoE < 8192 ? twoE : 8192);
    for (int i = tid; i < nscan; i += blockDim.x) {
        if (i & 1) oddOr |= words[i];
        long long j = twoE - 1 - i;
        if (j >= nscan && (j & 1)) oddOr |= words[j];
    }
    __shared__ unsigned int sred[16];
    for (int off = 32; off > 0; off >>= 1)
        oddOr |= (unsigned int)__shfl_down((int)oddOr, off, 64);
    int wid = tid >> 6;
    if ((tid & 63) == 0) sred[wid] = oddOr;
    __syncthreads();
    if (tid == 0) {
        unsigned int o = 0;
        for (int i = 0; i < (int)(blockDim.x >> 6); ++i) o |= sred[i];
        flags[0] = o ? 1 : 0;   // 1 = int32 layout
        flags[1] = 0x7fffffff;  // rmin (partition fills via atomicMin)
        flags[8] = 0;           // ovf count
    }
    for (int k = tid; k < nbkt; k += blockDim.x) gtail[k * GT_STRIDE] = k * segcap;
}

// W [64][N] f32 -> Wtb [N][64] bf16 (RNE) via padded LDS tile.
__global__ void LINK_transpose_kernel(const float* __restrict__ W,
                                      unsigned short* __restrict__ Wtb, int N) {
    __shared__ float tile[64][65];
    int n0 = blockIdx.x * 64;
    int lx = threadIdx.x & 63;
    int ly = threadIdx.x >> 6;
#pragma unroll
    for (int it = 0; it < 16; ++it) {
        int ch = ly + 4 * it;
        float v = 0.0f;
        if (n0 + lx < N) v = W[(size_t)ch * N + (n0 + lx)];
        tile[lx][ch] = v;
    }
    __syncthreads();
#pragma unroll
    for (int it = 0; it < 16; ++it) {
        int nn = ly + 4 * it;
        if (n0 + nn < N) {
            union { float f; unsigned int i; } x; x.f = tile[nn][lx];
            unsigned int u = x.i;
            unsigned int r = (u + 0x7fffu + ((u >> 16) & 1u)) >> 16;  // RNE
            Wtb[((size_t)(n0 + nn) << 6) + lx] = (unsigned short)r;
        }
    }
}

// Edges -> 256-row buckets. Records 4B: (r&255)<<17 | c. LDS-staged, wave-wide
// coalesced flushes. Also block-reduces rmin -> atomicMin(flags[1]).
__global__ __launch_bounds__(1024) void LINK_part_kernel(
    const unsigned int* __restrict__ words, int E, int N, int nbkt, int segcap,
    int* __restrict__ gtail, unsigned int* __restrict__ recs,
    int* __restrict__ ovf, int* __restrict__ flags) {
    __shared__ unsigned int lstage[NBKT_MAX * SLOTS];  // 57.6 KB
    __shared__ int lcnt[NBKT_MAX];
    __shared__ int sred[16];
    int tid = threadIdx.x;
    for (int k = tid; k < nbkt; k += blockDim.x) lcnt[k] = 0;
    __syncthreads();
    int isInt32 = flags[0];
    int mnr = 0x7fffffff;
    int nblk = gridDim.x;
    long long per_round = (long long)nblk * blockDim.x;
    long long nround = ((long long)E + per_round - 1) / per_round;
    int lane = tid & 63, wid = tid >> 6, nw = blockDim.x >> 6;
    for (long long rd = 0; rd < nround; ++rd) {
        long long e = (rd * nblk + blockIdx.x) * blockDim.x + tid;
        if (e < E) {
            int r, c;
            if (isInt32) {
                r = (int)__builtin_nontemporal_load(words + e);
                c = (int)__builtin_nontemporal_load(words + E + e);
            } else {
                r = (int)__builtin_nontemporal_load(words + 2 * e);
                c = (int)__builtin_nontemporal_load(words + 2LL * E + 2 * e);
            }
            mnr = min(mnr, r);
            if ((unsigned)r < (unsigned)N && (unsigned)c < (unsigned)N) {
                int k = r >> 8;
                unsigned int rec = ((unsigned int)(r & 255) << 17) | (unsigned int)c;
                int pos = atomicAdd(&lcnt[k], 1);
                if (pos < SLOTS) {
                    lstage[k * SLOTS + pos] = rec;
                } else {  // rare mid-round spill: direct global append
                    int g = atomicAdd(&gtail[k * GT_STRIDE], 1);
                    if (g < (k + 1) * segcap) recs[g] = rec;
                    else {
                        int oi = atomicAdd(&flags[8], 1);
                        if (oi < OVF_MAX) { ovf[2 * oi] = r; ovf[2 * oi + 1] = c; }
                    }
                }
            }
        }
        __syncthreads();
        bool last = (rd == nround - 1);
        for (int k = wid; k < nbkt; k += nw) {
            int cnt = lcnt[k]; if (cnt > SLOTS) cnt = SLOTS;
            if (cnt >= FLUSH_T || (last && cnt > 0)) {
                int g = 0;
                if (lane == 0) g = atomicAdd(&gtail[k * GT_STRIDE], cnt);
                g = __shfl(g, 0);
                if (lane < cnt) {
                    int gg = g + lane;
                    unsigned int rec = lstage[k * SLOTS + lane];
                    if (gg < (k + 1) * segcap) recs[gg] = rec;
                    else {
                        int oi = atomicAdd(&flags[8], 1);
                        if (oi < OVF_MAX) {
                            ovf[2 * oi] = (k << 8) | (int)(rec >> 17);
                            ovf[2 * oi + 1] = (int)(rec & 0x1FFFF);
                        }
                    }
                }
                if (lane == 0) lcnt[k] = 0;
            }
        }
        __syncthreads();
    }
    for (int off = 32; off > 0; off >>= 1) mnr = min(mnr, __shfl_down(mnr, off, 64));
    if (lane == 0) sred[wid] = mnr;
    __syncthreads();
    if (tid == 0) {
        int m = 0x7fffffff;
        for (int i = 0; i < 16; ++i) m = min(m, sred[i]);
        atomicMin(&flags[1], m);
    }
}

// Two sub-blocks per bucket, each owning 128 rows (LDS 32.5KB -> 4 blocks/CU,
// full 32-wave occupancy; R9's 65KB version measured 51%). Phase 1: bin this
// half's records into per-row LDS lists. Phase 2: proven row-gather — wave per
// row, lane=channel, 8 independent 128B Wtb loads, one coalesced store.
__global__ __launch_bounds__(512) void LINK_bgather_kernel(
    const int* __restrict__ gtail, const unsigned int* __restrict__ recs, int segcap,
    const unsigned short* __restrict__ Wtb, const float* __restrict__ bias,
    float* __restrict__ out, int* __restrict__ flags, int* __restrict__ ovf, int N) {
    __shared__ int lcols[128 * SL];  // 32 KB
    __shared__ int lcnt[128];
    int b = blockIdx.x >> 1;
    int sub = blockIdx.x & 1;
    int tid = threadIdx.x;
    for (int i = tid; i < 128; i += 512) lcnt[i] = 0;
    __syncthreads();
    int len = gtail[b * GT_STRIDE] - b * segcap;
    if (len > segcap) len = segcap;
    if (len < 0) len = 0;
    const unsigned int* rp = recs + (size_t)b * segcap;
    int subbit = sub << 7;
    for (int i = tid; i < len; i += 512) {
        unsigned int rec = rp[i];
        int lr = (int)(rec >> 17);
        if ((lr & 128) != subbit) continue;
        lr &= 127;
        int c = (int)(rec & 0x1FFFF);
        int pos = atomicAdd(&lcnt[lr], 1);
        if (pos < SL) {
            lcols[(lr << 6) + pos] = c;
        } else {  // astronomically rare: defer to global ovf cleanup (raw row)
            int oi = atomicAdd(&flags[8], 1);
            if (oi < OVF_MAX) { ovf[2 * oi] = (b << 8) | subbit | lr; ovf[2 * oi + 1] = c; }
        }
    }
    __syncthreads();
    int rmin = flags[1];
    int lane = tid & 63, wid = tid >> 6;  // 8 waves
    for (int lr = wid; lr < 128; lr += 8) {
        int cnt = lcnt[lr]; if (cnt > SL) cnt = SL;
        int base = lr << 6;
        float acc = 0.0f;
        int j = 0;
        for (; j + 8 <= cnt; j += 8) {
            int c0 = lcols[base + j + 0], c1 = lcols[base + j + 1];
            int c2 = lcols[base + j + 2], c3 = lcols[base + j + 3];
            int c4 = lcols[base + j + 4], c5 = lcols[base + j + 5];
            int c6 = lcols[base + j + 6], c7 = lcols[base + j + 7];
            unsigned short u0 = Wtb[((size_t)c0 << 6) + lane];
            unsigned short u1 = Wtb[((size_t)c1 << 6) + lane];
            unsigned short u2 = Wtb[((size_t)c2 << 6) + lane];
            unsigned short u3 = Wtb[((size_t)c3 << 6) + lane];
            unsigned short u4 = Wtb[((size_t)c4 << 6) + lane];
            unsigned short u5 = Wtb[((size_t)c5 << 6) + lane];
            unsigned short u6 = Wtb[((size_t)c6 << 6) + lane];
            unsigned short u7 = Wtb[((size_t)c7 << 6) + lane];
            float s01 = bf16u_to_f(u0) + bf16u_to_f(u1);
            float s23 = bf16u_to_f(u2) + bf16u_to_f(u3);
            float s45 = bf16u_to_f(u4) + bf16u_to_f(u5);
            float s67 = bf16u_to_f(u6) + bf16u_to_f(u7);
            acc += (s01 + s23) + (s45 + s67);
        }
        for (; j < cnt; ++j)
            acc += bf16u_to_f(Wtb[((size_t)lcols[base + j] << 6) + lane]);
        int orow = (b << 8) + subbit + lr - rmin;
        if ((unsigned)orow < (unsigned)N)
            out[((size_t)orow << 6) + lane] = acc + bias[lane];
    }
}

// Bias for out rows not covered by any bucket (only when rmin large; usually no-op).
__global__ void LINK_biastail_kernel(float* __restrict__ out, const float* __restrict__ bias,
                                     const int* __restrict__ flags, int N, int nbkt) {
    int rmin = flags[1];
    long long start = (long long)nbkt * 256 - (long long)rmin;
    if (start < 0) start = 0;
    if (start >= N) return;
    long long total = ((long long)N - start) * 64;
    long long base = start * 64;
    long long i0 = (long long)blockIdx.x * blockDim.x + threadIdx.x;
    long long stride = (long long)gridDim.x * blockDim.x;
    for (long long i = i0; i < total; i += stride) out[base + i] = bias[(int)(i & 63)];
}

// Cleanup for spilled edges (expected zero on real data). ovf[2i] = raw row.
__global__ void LINK_ovf_kernel(const int* __restrict__ ovf, const int* __restrict__ flags,
                                const unsigned short* __restrict__ Wtb,
                                float* __restrict__ out, int N) {
    int g = blockIdx.x * blockDim.x + threadIdx.x;
    int w = g >> 6, lane = g & 63;
    int cnt = flags[8]; if (cnt > OVF_MAX) cnt = OVF_MAX;
    if (cnt == 0) return;
    int rmin = flags[1];
    int nw = (gridDim.x * blockDim.x) >> 6;
    for (int i = w; i < cnt; i += nw) {
        int r = ovf[2 * i] - rmin;
        int c = ovf[2 * i + 1];
        if ((unsigned)r >= (unsigned)N || (unsigned)c >= (unsigned)N) continue;
        atomicAdd(&out[((size_t)r << 6) + lane], bf16u_to_f(Wtb[((size_t)c << 6) + lane]));
    }
}

// ---- Fallback path for unexpected shapes/ws: analyze + bias init + scatter ----
__global__ void LINK_initout_kernel(float* __restrict__ out, const float* __restrict__ b,
                                    int total, int* __restrict__ flags) {
    int i = blockIdx.x * blockDim.x + threadIdx.x;
    if (i == 0) { flags[0] = 0; flags[1] = 0x7fffffff; flags[2] = 0x7fffffff; }
    if (i < total) out[i] = b[i & 63];
}

__global__ __launch_bounds__(256) void LINK_analyze_kernel(
    const unsigned int* __restrict__ words, int E, int* __restrict__ flags) {
    const uint4* __restrict__ w4 = (const uint4*)words;
    int tid = blockIdx.x * blockDim.x + threadIdx.x;
    int nth = gridDim.x * blockDim.x;
    int n1 = E >> 2;
    long long twoE = 2LL * E;
    int n2 = (int)(twoE >> 2);
    unsigned int oddOr = 0u;
    int mn32 = 0x7fffffff, mn64 = 0x7fffffff;
    for (int i = tid; i < n2; i += nth) {
        uint4 w = w4[i];
        oddOr |= (w.y | w.w);
        mn64 = min(mn64, min((int)w.x, (int)w.z));
        if (i < n1)
            mn32 = min(mn32, min(min((int)w.x, (int)w.y), min((int)w.z, (int)w.w)));
    }
    for (long long i = ((long long)n1 << 2) + tid; i < E; i += nth)
        mn32 = min(mn32, (int)words[i]);
    for (long long i = ((long long)n2 << 2) + tid; i < twoE; i += nth) {
        unsigned int w = words[i];
        if (i & 1) oddOr |= w; else mn64 = min(mn64, (int)w);
    }
    for (int off = 32; off > 0; off >>= 1) {
        oddOr |= (unsigned int)__shfl_down((int)oddOr, off, 64);
        mn32 = min(mn32, __shfl_down(mn32, off, 64));
        mn64 = min(mn64, __shfl_down(mn64, off, 64));
    }
    __shared__ int s_or[4], s_m32[4], s_m64[4];
    int wid = threadIdx.x >> 6;
    if ((threadIdx.x & 63) == 0) { s_or[wid] = (int)oddOr; s_m32[wid] = mn32; s_m64[wid] = mn64; }
    __syncthreads();
    if (threadIdx.x == 0) {
        int o = s_or[0] | s_or[1] | s_or[2] | s_or[3];
        int a = min(min(s_m32[0], s_m32[1]), min(s_m32[2], s_m32[3]));
        int d = min(min(s_m64[0], s_m64[1]), min(s_m64[2], s_m64[3]));
        if (o) atomicOr(&flags[0], 1);
        atomicMin(&flags[1], a);
        atomicMin(&flags[2], d);
    }
}

__global__ void LINK_scatter_kernel(const unsigned int* __restrict__ words, int E,
                                    const float* __restrict__ W,
                                    float* __restrict__ out,
                                    const int* __restrict__ flags, int N) {
    long long g = (long long)blockIdx.x * blockDim.x + threadIdx.x;
    int e = (int)(g >> 6);
    if (e >= E) return;
    int ch = (int)(g & 63);
    int r, c, rmin;
    if (flags[0]) { r = (int)words[e]; c = (int)words[E + e]; rmin = flags[1]; }
    else { r = (int)words[2LL * e]; c = (int)words[2LL * (E + e)]; rmin = flags[2]; }
    r -= rmin;
    if ((unsigned)r >= (unsigned)N || (unsigned)c >= (unsigned)N) return;
    atomicAdd(&out[((size_t)r << 6) + ch], W[(size_t)ch * N + c]);
}

static inline size_t align256(size_t x) { return (x + 255) & ~(size_t)255; }

extern "C" void kernel_launch(void* const* d_in, const int* in_sizes, int n_in,
                              void* d_out, int out_size, void* d_ws, size_t ws_size,
                              hipStream_t stream) {
    const unsigned int* words = (const unsigned int*)d_in[0];
    const float* W = (const float*)d_in[1];
    const float* b = (const float*)d_in[2];
    float* out = (float*)d_out;

    int E = in_sizes[0] / 2;   // 3,200,000
    int N = in_sizes[1] / 64;  // 100,000
    int total = out_size;      // N*64
    int nbkt = (N + 255) / 256;  // 391

    size_t off_flags = 0;
    size_t off_wtb   = align256(off_flags + 256 * sizeof(int));
    size_t off_gtail = align256(off_wtb + (size_t)N * 64 * sizeof(unsigned short));
    size_t off_ovf   = align256(off_gtail + (size_t)NBKT_MAX * GT_STRIDE * sizeof(int));
    size_t off_recs  = align256(off_ovf + (size_t)OVF_MAX * 2 * sizeof(int));

    int* flags = (int*)((char*)d_ws + off_flags);
    unsigned short* Wtb = (unsigned short*)((char*)d_ws + off_wtb);
    int* gtail = (int*)((char*)d_ws + off_gtail);
    int* ovf   = (int*)((char*)d_ws + off_ovf);
    unsigned int* recs = (unsigned int*)((char*)d_ws + off_recs);

    long long avail = (ws_size > off_recs)
        ? (long long)((ws_size - off_recs) / ((size_t)nbkt * sizeof(int))) : 0;
    int segcap = (int)(avail > 16384 ? 16384 : avail);
    int avg = (int)((long long)E / (nbkt > 0 ? nbkt : 1)) + 1;
    bool useMain = (N <= (1 << 17)) && (nbkt <= NBKT_MAX) &&
                   (segcap >= avg + avg / 4 + SLOTS) && (E > 0);

    if (useMain) {
        LINK_detect_kernel<<<1, 1024, 0, stream>>>(words, E, flags, gtail, nbkt, segcap);
        LINK_transpose_kernel<<<(N + 63) / 64, 256, 0, stream>>>(W, Wtb, N);
        LINK_part_kernel<<<512, 1024, 0, stream>>>(words, E, N, nbkt, segcap,
                                                   gtail, recs, ovf, flags);
        LINK_bgather_kernel<<<nbkt * 2, 512, 0, stream>>>(gtail, recs, segcap, Wtb, b,
                                                          out, flags, ovf, N);
        LINK_biastail_kernel<<<64, 256, 0, stream>>>(out, b, flags, N, nbkt);
        LINK_ovf_kernel<<<64, 256, 0, stream>>>(ovf, flags, Wtb, out, N);
    } else {
        LINK_initout_kernel<<<(total + 255) / 256, 256, 0, stream>>>(out, b, total, flags);
        LINK_analyze_kernel<<<256, 256, 0, stream>>>(words, E, flags);
        long long tthreads = (long long)E * 64;
        LINK_scatter_kernel<<<(int)((tthreads + 255) / 256), 256, 0, stream>>>(
            words, E, W, out, flags, N);
    }
}

// Round 11
// 227.494 us; speedup vs baseline: 6.9004x; 1.0062x over previous
//
#include <hip/hip_runtime.h>

// out[r*64+ch] = b[ch] + sum_{edges (r,c)} W[ch][c],  r normalized by row.min().
// N = 100000, C = 64, E = 3.2M.
//
// R11: R10 pipeline; bgather rebuilt for memory-level parallelism. R10 showed
//  occupancy% was a decay artifact (single-shot dispatch), and bgather is
//  latency*concurrency bound: 17KB in flight/CU at ~600ns => 5.3 TB/s. Fix:
//  16 independent 128B Wtb loads per wave (VGPR-budgeted via launch_bounds
//  (256,8) -> 64 VGPR cap, 8 waves/SIMD), 4 sub-blocks of 64 rows per bucket.
//  Lessons kept: no shfl-broadcast-per-record accum (R3/R7 ~1410us twice);
//  no same-line global atomics (R5); row-gather w/ independent loads (R6/R9).
// ws: flags | Wtb[N*64 bf16] | gtail[nbkt*16] | ovf | recs[nbkt*segcap]

#define OVF_MAX (1 << 19)
#define NBKT_MAX 400
#define SLOTS 36
#define FLUSH_T 24
#define GT_STRIDE 16
#define SL 64           // LDS col-list slots per row

__device__ __forceinline__ float bf16u_to_f(unsigned short u) {
    union { unsigned int i; float f; } x; x.i = ((unsigned int)u) << 16; return x.f;
}

// 1 block: dtype probe (head+tail odd words) + flags/gtail init.
__global__ __launch_bounds__(1024) void LINK_detect_kernel(
    const unsigned int* __restrict__ words, int E, int* __restrict__ flags,
    int* __restrict__ gtail, int nbkt, int segcap) {
    long long twoE = 2LL * E;
    int tid = threadIdx.x;
    unsigned int oddOr = 0u;
    int nscan = (int)(twoE < 8192 ? twoE : 8192);
    for (int i = tid; i < nscan; i += blockDim.x) {
        if (i & 1) oddOr |= words[i];
        long long j = twoE - 1 - i;
        if (j >= nscan && (j & 1)) oddOr |= words[j];
    }
    __shared__ unsigned int sred[16];
    for (int off = 32; off > 0; off >>= 1)
        oddOr |= (unsigned int)__shfl_down((int)oddOr, off, 64);
    int wid = tid >> 6;
    if ((tid & 63) == 0) sred[wid] = oddOr;
    __syncthreads();
    if (tid == 0) {
        unsigned int o = 0;
        for (int i = 0; i < (int)(blockDim.x >> 6); ++i) o |= sred[i];
        flags[0] = o ? 1 : 0;   // 1 = int32 layout
        flags[1] = 0x7fffffff;  // rmin (partition fills via atomicMin)
        flags[8] = 0;           // ovf count
    }
    for (int k = tid; k < nbkt; k += blockDim.x) gtail[k * GT_STRIDE] = k * segcap;
}

// W [64][N] f32 -> Wtb [N][64] bf16 (RNE) via padded LDS tile.
__global__ void LINK_transpose_kernel(const float* __restrict__ W,
                                      unsigned short* __restrict__ Wtb, int N) {
    __shared__ float tile[64][65];
    int n0 = blockIdx.x * 64;
    int lx = threadIdx.x & 63;
    int ly = threadIdx.x >> 6;
#pragma unroll
    for (int it = 0; it < 16; ++it) {
        int ch = ly + 4 * it;
        float v = 0.0f;
        if (n0 + lx < N) v = W[(size_t)ch * N + (n0 + lx)];
        tile[lx][ch] = v;
    }
    __syncthreads();
#pragma unroll
    for (int it = 0; it < 16; ++it) {
        int nn = ly + 4 * it;
        if (n0 + nn < N) {
            union { float f; unsigned int i; } x; x.f = tile[nn][lx];
            unsigned int u = x.i;
            unsigned int r = (u + 0x7fffu + ((u >> 16) & 1u)) >> 16;  // RNE
            Wtb[((size_t)(n0 + nn) << 6) + lx] = (unsigned short)r;
        }
    }
}

// Edges -> 256-row buckets. Records 4B: (r&255)<<17 | c. LDS-staged, wave-wide
// coalesced flushes. Also block-reduces rmin -> atomicMin(flags[1]).
__global__ __launch_bounds__(1024) void LINK_part_kernel(
    const unsigned int* __restrict__ words, int E, int N, int nbkt, int segcap,
    int* __restrict__ gtail, unsigned int* __restrict__ recs,
    int* __restrict__ ovf, int* __restrict__ flags) {
    __shared__ unsigned int lstage[NBKT_MAX * SLOTS];  // 57.6 KB
    __shared__ int lcnt[NBKT_MAX];
    __shared__ int sred[16];
    int tid = threadIdx.x;
    for (int k = tid; k < nbkt; k += blockDim.x) lcnt[k] = 0;
    __syncthreads();
    int isInt32 = flags[0];
    int mnr = 0x7fffffff;
    int nblk = gridDim.x;
    long long per_round = (long long)nblk * blockDim.x;
    long long nround = ((long long)E + per_round - 1) / per_round;
    int lane = tid & 63, wid = tid >> 6, nw = blockDim.x >> 6;
    for (long long rd = 0; rd < nround; ++rd) {
        long long e = (rd * nblk + blockIdx.x) * blockDim.x + tid;
        if (e < E) {
            int r, c;
            if (isInt32) {
                r = (int)__builtin_nontemporal_load(words + e);
                c = (int)__builtin_nontemporal_load(words + E + e);
            } else {
                r = (int)__builtin_nontemporal_load(words + 2 * e);
                c = (int)__builtin_nontemporal_load(words + 2LL * E + 2 * e);
            }
            mnr = min(mnr, r);
            if ((unsigned)r < (unsigned)N && (unsigned)c < (unsigned)N) {
                int k = r >> 8;
                unsigned int rec = ((unsigned int)(r & 255) << 17) | (unsigned int)c;
                int pos = atomicAdd(&lcnt[k], 1);
                if (pos < SLOTS) {
                    lstage[k * SLOTS + pos] = rec;
                } else {  // rare mid-round spill: direct global append
                    int g = atomicAdd(&gtail[k * GT_STRIDE], 1);
                    if (g < (k + 1) * segcap) recs[g] = rec;
                    else {
                        int oi = atomicAdd(&flags[8], 1);
                        if (oi < OVF_MAX) { ovf[2 * oi] = r; ovf[2 * oi + 1] = c; }
                    }
                }
            }
        }
        __syncthreads();
        bool last = (rd == nround - 1);
        for (int k = wid; k < nbkt; k += nw) {
            int cnt = lcnt[k]; if (cnt > SLOTS) cnt = SLOTS;
            if (cnt >= FLUSH_T || (last && cnt > 0)) {
                int g = 0;
                if (lane == 0) g = atomicAdd(&gtail[k * GT_STRIDE], cnt);
                g = __shfl(g, 0);
                if (lane < cnt) {
                    int gg = g + lane;
                    unsigned int rec = lstage[k * SLOTS + lane];
                    if (gg < (k + 1) * segcap) recs[gg] = rec;
                    else {
                        int oi = atomicAdd(&flags[8], 1);
                        if (oi < OVF_MAX) {
                            ovf[2 * oi] = (k << 8) | (int)(rec >> 17);
                            ovf[2 * oi + 1] = (int)(rec & 0x1FFFF);
                        }
                    }
                }
                if (lane == 0) lcnt[k] = 0;
            }
        }
        __syncthreads();
    }
    for (int off = 32; off > 0; off >>= 1) mnr = min(mnr, __shfl_down(mnr, off, 64));
    if (lane == 0) sred[wid] = mnr;
    __syncthreads();
    if (tid == 0) {
        int m = 0x7fffffff;
        for (int i = 0; i < 16; ++i) m = min(m, sred[i]);
        atomicMin(&flags[1], m);
    }
}

// Four sub-blocks per bucket, each owning 64 rows (256 thr, 16.6KB LDS).
// Phase 1: bin this quarter's records into per-row LDS lists. Phase 2: row
// gather — wave per row, lane=channel, SIXTEEN independent 128B Wtb loads in
// flight (R10 measured the 8-deep version latency*concurrency bound at 5.3
// TB/s effective). launch_bounds(256,8) caps VGPR at 64 for 8 waves/SIMD.
__global__ __launch_bounds__(256, 8) void LINK_bgather_kernel(
    const int* __restrict__ gtail, const unsigned int* __restrict__ recs, int segcap,
    const unsigned short* __restrict__ Wtb, const float* __restrict__ bias,
    float* __restrict__ out, int* __restrict__ flags, int* __restrict__ ovf, int N) {
    __shared__ int lcols[64 * SL];  // 16 KB
    __shared__ int lcnt[64];
    int b = blockIdx.x >> 2;
    int sub = blockIdx.x & 3;
    int tid = threadIdx.x;
    if (tid < 64) lcnt[tid] = 0;
    __syncthreads();
    int len = gtail[b * GT_STRIDE] - b * segcap;
    if (len > segcap) len = segcap;
    if (len < 0) len = 0;
    const unsigned int* rp = recs + (size_t)b * segcap;
    for (int i = tid; i < len; i += 256) {
        unsigned int rec = rp[i];
        int lrf = (int)(rec >> 17);
        if ((lrf >> 6) != sub) continue;
        int lr = lrf & 63;
        int c = (int)(rec & 0x1FFFF);
        int pos = atomicAdd(&lcnt[lr], 1);
        if (pos < SL) {
            lcols[(lr << 6) + pos] = c;
        } else {  // astronomically rare: defer to global ovf cleanup (raw row)
            int oi = atomicAdd(&flags[8], 1);
            if (oi < OVF_MAX) { ovf[2 * oi] = (b << 8) | lrf; ovf[2 * oi + 1] = c; }
        }
    }
    __syncthreads();
    int rmin = flags[1];
    int lane = tid & 63, wid = tid >> 6;  // 4 waves
    for (int lr = wid; lr < 64; lr += 4) {
        int cnt = lcnt[lr]; if (cnt > SL) cnt = SL;
        int base = lr << 6;
        float acc = 0.0f;
        int j = 0;
        for (; j + 16 <= cnt; j += 16) {
            int c0 = lcols[base + j + 0], c1 = lcols[base + j + 1];
            int c2 = lcols[base + j + 2], c3 = lcols[base + j + 3];
            int c4 = lcols[base + j + 4], c5 = lcols[base + j + 5];
            int c6 = lcols[base + j + 6], c7 = lcols[base + j + 7];
            int c8 = lcols[base + j + 8], c9 = lcols[base + j + 9];
            int cA = lcols[base + j + 10], cB = lcols[base + j + 11];
            int cC = lcols[base + j + 12], cD = lcols[base + j + 13];
            int cE = lcols[base + j + 14], cF = lcols[base + j + 15];
            unsigned short u0 = Wtb[((size_t)c0 << 6) + lane];
            unsigned short u1 = Wtb[((size_t)c1 << 6) + lane];
            unsigned short u2 = Wtb[((size_t)c2 << 6) + lane];
            unsigned short u3 = Wtb[((size_t)c3 << 6) + lane];
            unsigned short u4 = Wtb[((size_t)c4 << 6) + lane];
            unsigned short u5 = Wtb[((size_t)c5 << 6) + lane];
            unsigned short u6 = Wtb[((size_t)c6 << 6) + lane];
            unsigned short u7 = Wtb[((size_t)c7 << 6) + lane];
            unsigned short u8 = Wtb[((size_t)c8 << 6) + lane];
            unsigned short u9 = Wtb[((size_t)c9 << 6) + lane];
            unsigned short uA = Wtb[((size_t)cA << 6) + lane];
            unsigned short uB = Wtb[((size_t)cB << 6) + lane];
            unsigned short uC = Wtb[((size_t)cC << 6) + lane];
            unsigned short uD = Wtb[((size_t)cD << 6) + lane];
            unsigned short uE = Wtb[((size_t)cE << 6) + lane];
            unsigned short uF = Wtb[((size_t)cF << 6) + lane];
            float s0 = (bf16u_to_f(u0) + bf16u_to_f(u1)) + (bf16u_to_f(u2) + bf16u_to_f(u3));
            float s1 = (bf16u_to_f(u4) + bf16u_to_f(u5)) + (bf16u_to_f(u6) + bf16u_to_f(u7));
            float s2 = (bf16u_to_f(u8) + bf16u_to_f(u9)) + (bf16u_to_f(uA) + bf16u_to_f(uB));
            float s3 = (bf16u_to_f(uC) + bf16u_to_f(uD)) + (bf16u_to_f(uE) + bf16u_to_f(uF));
            acc += (s0 + s1) + (s2 + s3);
        }
        for (; j + 8 <= cnt; j += 8) {
            int c0 = lcols[base + j + 0], c1 = lcols[base + j + 1];
            int c2 = lcols[base + j + 2], c3 = lcols[base + j + 3];
            int c4 = lcols[base + j + 4], c5 = lcols[base + j + 5];
            int c6 = lcols[base + j + 6], c7 = lcols[base + j + 7];
            unsigned short u0 = Wtb[((size_t)c0 << 6) + lane];
            unsigned short u1 = Wtb[((size_t)c1 << 6) + lane];
            unsigned short u2 = Wtb[((size_t)c2 << 6) + lane];
            unsigned short u3 = Wtb[((size_t)c3 << 6) + lane];
            unsigned short u4 = Wtb[((size_t)c4 << 6) + lane];
            unsigned short u5 = Wtb[((size_t)c5 << 6) + lane];
            unsigned short u6 = Wtb[((size_t)c6 << 6) + lane];
            unsigned short u7 = Wtb[((size_t)c7 << 6) + lane];
            float s0 = (bf16u_to_f(u0) + bf16u_to_f(u1)) + (bf16u_to_f(u2) + bf16u_to_f(u3));
            float s1 = (bf16u_to_f(u4) + bf16u_to_f(u5)) + (bf16u_to_f(u6) + bf16u_to_f(u7));
            acc += s0 + s1;
        }
        for (; j < cnt; ++j)
            acc += bf16u_to_f(Wtb[((size_t)lcols[base + j] << 6) + lane]);
        int orow = (b << 8) + (sub << 6) + lr - rmin;
        if ((unsigned)orow < (unsigned)N)
            out[((size_t)orow << 6) + lane] = acc + bias[lane];
    }
}

// Bias for out rows not covered by any bucket (only when rmin large; usually no-op).
__global__ void LINK_biastail_kernel(float* __restrict__ out, const float* __restrict__ bias,
                                     const int* __restrict__ flags, int N, int nbkt) {
    int rmin = flags[1];
    long long start = (long long)nbkt * 256 - (long long)rmin;
    if (start < 0) start = 0;
    if (start >= N) return;
    long long total = ((long long)N - start) * 64;
    long long base = start * 64;
    long long i0 = (long long)blockIdx.x * blockDim.x + threadIdx.x;
    long long stride = (long long)gridDim.x * blockDim.x;
    for (long long i = i0; i < total; i += stride) out[base + i] = bias[(int)(i & 63)];
}

// Cleanup for spilled edges (expected zero on real data). ovf[2i] = raw row.
__global__ void LINK_ovf_kernel(const int* __restrict__ ovf, const int* __restrict__ flags,
                                const unsigned short* __restrict__ Wtb,
                                float* __restrict__ out, int N) {
    int g = blockIdx.x * blockDim.x + threadIdx.x;
    int w = g >> 6, lane = g & 63;
    int cnt = flags[8]; if (cnt > OVF_MAX) cnt = OVF_MAX;
    if (cnt == 0) return;
    int rmin = flags[1];
    int nw = (gridDim.x * blockDim.x) >> 6;
    for (int i = w; i < cnt; i += nw) {
        int r = ovf[2 * i] - rmin;
        int c = ovf[2 * i + 1];
        if ((unsigned)r >= (unsigned)N || (unsigned)c >= (unsigned)N) continue;
        atomicAdd(&out[((size_t)r << 6) + lane], bf16u_to_f(Wtb[((size_t)c << 6) + lane]));
    }
}

// ---- Fallback path for unexpected shapes/ws: analyze + bias init + scatter ----
__global__ void LINK_initout_kernel(float* __restrict__ out, const float* __restrict__ b,
                                    int total, int* __restrict__ flags) {
    int i = blockIdx.x * blockDim.x + threadIdx.x;
    if (i == 0) { flags[0] = 0; flags[1] = 0x7fffffff; flags[2] = 0x7fffffff; }
    if (i < total) out[i] = b[i & 63];
}

__global__ __launch_bounds__(256) void LINK_analyze_kernel(
    const unsigned int* __restrict__ words, int E, int* __restrict__ flags) {
    const uint4* __restrict__ w4 = (const uint4*)words;
    int tid = blockIdx.x * blockDim.x + threadIdx.x;
    int nth = gridDim.x * blockDim.x;
    int n1 = E >> 2;
    long long twoE = 2LL * E;
    int n2 = (int)(twoE >> 2);
    unsigned int oddOr = 0u;
    int mn32 = 0x7fffffff, mn64 = 0x7fffffff;
    for (int i = tid; i < n2; i += nth) {
        uint4 w = w4[i];
        oddOr |= (w.y | w.w);
        mn64 = min(mn64, min((int)w.x, (int)w.z));
        if (i < n1)
            mn32 = min(mn32, min(min((int)w.x, (int)w.y), min((int)w.z, (int)w.w)));
    }
    for (long long i = ((long long)n1 << 2) + tid; i < E; i += nth)
        mn32 = min(mn32, (int)words[i]);
    for (long long i = ((long long)n2 << 2) + tid; i < twoE; i += nth) {
        unsigned int w = words[i];
        if (i & 1) oddOr |= w; else mn64 = min(mn64, (int)w);
    }
    for (int off = 32; off > 0; off >>= 1) {
        oddOr |= (unsigned int)__shfl_down((int)oddOr, off, 64);
        mn32 = min(mn32, __shfl_down(mn32, off, 64));
        mn64 = min(mn64, __shfl_down(mn64, off, 64));
    }
    __shared__ int s_or[4], s_m32[4], s_m64[4];
    int wid = threadIdx.x >> 6;
    if ((threadIdx.x & 63) == 0) { s_or[wid] = (int)oddOr; s_m32[wid] = mn32; s_m64[wid] = mn64; }
    __syncthreads();
    if (threadIdx.x == 0) {
        int o = s_or[0] | s_or[1] | s_or[2] | s_or[3];
        int a = min(min(s_m32[0], s_m32[1]), min(s_m32[2], s_m32[3]));
        int d = min(min(s_m64[0], s_m64[1]), min(s_m64[2], s_m64[3]));
        if (o) atomicOr(&flags[0], 1);
        atomicMin(&flags[1], a);
        atomicMin(&flags[2], d);
    }
}

__global__ void LINK_scatter_kernel(const unsigned int* __restrict__ words, int E,
                                    const float* __restrict__ W,
                                    float* __restrict__ out,
                                    const int* __restrict__ flags, int N) {
    long long g = (long long)blockIdx.x * blockDim.x + threadIdx.x;
    int e = (int)(g >> 6);
    if (e >= E) return;
    int ch = (int)(g & 63);
    int r, c, rmin;
    if (flags[0]) { r = (int)words[e]; c = (int)words[E + e]; rmin = flags[1]; }
    else { r = (int)words[2LL * e]; c = (int)words[2LL * (E + e)]; rmin = flags[2]; }
    r -= rmin;
    if ((unsigned)r >= (unsigned)N || (unsigned)c >= (unsigned)N) return;
    atomicAdd(&out[((size_t)r << 6) + ch], W[(size_t)ch * N + c]);
}

static inline size_t align256(size_t x) { return (x + 255) & ~(size_t)255; }

extern "C" void kernel_launch(void* const* d_in, const int* in_sizes, int n_in,
                              void* d_out, int out_size, void* d_ws, size_t ws_size,
                              hipStream_t stream) {
    const unsigned int* words = (const unsigned int*)d_in[0];
    const float* W = (const float*)d_in[1];
    const float* b = (const float*)d_in[2];
    float* out = (float*)d_out;

    int E = in_sizes[0] / 2;   // 3,200,000
    int N = in_sizes[1] / 64;  // 100,000
    int total = out_size;      // N*64
    int nbkt = (N + 255) / 256;  // 391

    size_t off_flags = 0;
    size_t off_wtb   = align256(off_flags + 256 * sizeof(int));
    size_t off_gtail = align256(off_wtb + (size_t)N * 64 * sizeof(unsigned short));
    size_t off_ovf   = align256(off_gtail + (size_t)NBKT_MAX * GT_STRIDE * sizeof(int));
    size_t off_recs  = align256(off_ovf + (size_t)OVF_MAX * 2 * sizeof(int));

    int* flags = (int*)((char*)d_ws + off_flags);
    unsigned short* Wtb = (unsigned short*)((char*)d_ws + off_wtb);
    int* gtail = (int*)((char*)d_ws + off_gtail);
    int* ovf   = (int*)((char*)d_ws + off_ovf);
    unsigned int* recs = (unsigned int*)((char*)d_ws + off_recs);

    long long avail = (ws_size > off_recs)
        ? (long long)((ws_size - off_recs) / ((size_t)nbkt * sizeof(int))) : 0;
    int segcap = (int)(avail > 16384 ? 16384 : avail);
    int avg = (int)((long long)E / (nbkt > 0 ? nbkt : 1)) + 1;
    bool useMain = (N <= (1 << 17)) && (nbkt <= NBKT_MAX) &&
                   (segcap >= avg + avg / 4 + SLOTS) && (E > 0);

    if (useMain) {
        LINK_detect_kernel<<<1, 1024, 0, stream>>>(words, E, flags, gtail, nbkt, segcap);
        LINK_transpose_kernel<<<(N + 63) / 64, 256, 0, stream>>>(W, Wtb, N);
        LINK_part_kernel<<<512, 1024, 0, stream>>>(words, E, N, nbkt, segcap,
                                                   gtail, recs, ovf, flags);
        LINK_bgather_kernel<<<nbkt * 4, 256, 0, stream>>>(gtail, recs, segcap, Wtb, b,
                                                          out, flags, ovf, N);
        LINK_biastail_kernel<<<64, 256, 0, stream>>>(out, b, flags, N, nbkt);
        LINK_ovf_kernel<<<64, 256, 0, stream>>>(ovf, flags, Wtb, out, N);
    } else {
        LINK_initout_kernel<<<(total + 255) / 256, 256, 0, stream>>>(out, b, total, flags);
        LINK_analyze_kernel<<<256, 256, 0, stream>>>(words, E, flags);
        long long tthreads = (long long)E * 64;
        LINK_scatter_kernel<<<(int)((tthreads + 255) / 256), 256, 0, stream>>>(
            words, E, W, out, flags, N);
    }
}